// Round 5
// baseline (54.434 us; speedup 1.0000x reference)
//
#include <hip/hip_runtime.h>
#include <hip/hip_bf16.h>
#include <stdint.h>

// Problem geometry
#define NB 64          // batch
#define NC 64          // C_IN
#define NU 2048        // N_UNITS
#define K_REAL 1296    // H*W = 36*36
#define K_PAD  1408    // split0: 768 (12 tiles of 64), split1: 640 (10 tiles)
#define M_ROWS 4096    // NB*NC
#define K_SPLIT0 768

typedef __attribute__((ext_vector_type(4))) float f32x4;
typedef __attribute__((ext_vector_type(8))) short bf16x8;

__device__ __forceinline__ unsigned short f2bf_rne(float f) {
  union { float f; uint32_t u; } v; v.f = f;
  uint32_t u = v.u;
  return (unsigned short)((u + 0x7FFFu + ((u >> 16) & 1u)) >> 16);
}

// Convert fp32 [rows][K_REAL] -> bf16 [rows][K_PAD], zero-filling the pad.
// Handles x (rows 0..4095) and sw (rows 4096..6143) in one launch.
__global__ void convert_pad_kernel(const float* __restrict__ x,
                                   const float* __restrict__ sw,
                                   unsigned short* __restrict__ dst) {
  const int KB = K_PAD / 8;  // 176
  const int total = (M_ROWS + NU) * KB;
  for (int idx = blockIdx.x * blockDim.x + threadIdx.x; idx < total;
       idx += gridDim.x * blockDim.x) {
    int r  = idx / KB;
    int kb = idx - r * KB;
    int k0 = kb * 8;
    uint32_t p0 = 0, p1 = 0, p2 = 0, p3 = 0;
    if (k0 + 8 <= K_REAL) {
      const float* srow = (r < M_ROWS) ? (x + (size_t)r * K_REAL)
                                       : (sw + (size_t)(r - M_ROWS) * K_REAL);
      const float4* s = (const float4*)(srow + k0);
      float4 f0 = s[0];
      float4 f1 = s[1];
      p0 = (uint32_t)f2bf_rne(f0.x) | ((uint32_t)f2bf_rne(f0.y) << 16);
      p1 = (uint32_t)f2bf_rne(f0.z) | ((uint32_t)f2bf_rne(f0.w) << 16);
      p2 = (uint32_t)f2bf_rne(f1.x) | ((uint32_t)f2bf_rne(f1.y) << 16);
      p3 = (uint32_t)f2bf_rne(f1.z) | ((uint32_t)f2bf_rne(f1.w) << 16);
    }
    uint4 o; o.x = p0; o.y = p1; o.z = p2; o.w = p3;
    *(uint4*)(dst + (size_t)r * K_PAD + k0) = o;
  }
}

// ---------------------------------------------------------------------------
// 256x256 8-phase fused GEMM.  G[(b,c),u] = sum_hw A[(b,c),hw]*B[u,hw];
// epilogue: part[split][b][u] = sum_c fw[u,c]*G.  8 waves (2M x 4N), BK=64.
// LDS: [buf][A|B][ks][256 rows][32 bf16] - four 16KB ks-half planes per buf.
// Swizzle (involution on 16B chunks, bits 0-1 of chunk idx ^= bits 3-4):
//   write: LDS phys chunk pc holds global chunk pc ^ ((pc>>3)&3)
//   read : phys = logical ^ (((logical>>7)&3)<<4)
// Pipeline (2 K-tiles T0,T1 per 8-phase iter; regions die 1 phase before
// their slot is re-staged; every wait counted at vmcnt(10) except drain iter):
//   P1: rd T0.A(k0,mh0)+T0.B(k0) | stage T1.Ak1   | MFMA
//   P2: rd T0.A(k0,mh1)          | stage N0.Bk0   | MFMA | vm(10)
//   P3: rd T0.A(k1,mh0)+T0.B(k1) | stage N0.Ak0   | MFMA
//   P4: rd T0.A(k1,mh1)          | stage N0.Bk1   | MFMA | vm(10)
//   P5..P8: same on T1 (buf1), staging N0.Ak1, N1.Bk0, N1.Ak0, N1.Bk1
//   (N1.Ak1 is staged by the next iter's P1.)
// ---------------------------------------------------------------------------
__global__ __launch_bounds__(512, 1)
void fused_readout_gemm(const unsigned short* __restrict__ Abf,  // [M_ROWS][K_PAD]
                        const unsigned short* __restrict__ Bbf,  // [NU][K_PAD]
                        const float* __restrict__ fw,            // [NU][NC]
                        float* __restrict__ part) {              // [2][NB][NU]
  __shared__ unsigned short lds[2][2][2][8192];  // [buf][A/B][ks][16KB]

  const int tid  = threadIdx.x;
  const int lane = tid & 63;
  const int w    = tid >> 6;
  const int wm   = w >> 2;      // 0..1
  const int wn   = w & 3;       // 0..3
  const int g    = lane >> 4;   // k-group 0..3
  const int rl   = lane & 15;

  // XCD swizzle: 256 blocks, 8 chunks of 32.
  const int braw  = (int)blockIdx.x;
  const int bid   = (braw & 7) * 32 + (braw >> 3);
  const int split = bid >> 7;          // 0..1
  const int tileM = (bid >> 3) & 15;   // 0..15
  const int tileN = bid & 7;           // 0..7
  const int rowA0 = tileM * 256;
  const int colB0 = tileN * 256;
  const int kS    = split * K_SPLIT0;
  const int niters = (12 - 2 * split) >> 1;   // 6 or 5

  // Staging source (pre-swizzled): thread stages phys chunks {tid, 512+tid};
  // logical chunk = phys ^ ((phys>>3)&3); row = lc>>2 (+128 for load 1),
  // col-chunk = lc&3.
  const int lc0   = tid ^ ((tid >> 3) & 3);
  const int srow0 = lc0 >> 2;
  const int sc0   = lc0 & 3;
  const unsigned short* srcA = Abf + (size_t)(rowA0 + srow0) * K_PAD + kS + sc0 * 8;
  const unsigned short* srcB = Bbf + (size_t)(colB0 + srow0) * K_PAD + kS + sc0 * 8;

  // Read-side lane offset (bytes within a 16KB plane), swizzle folded in.
  const int laneOff = rl * 64 + ((g * 16) ^ (((rl >> 1) & 3) << 4));

#define AP(b, s) (&lds[b][0][s][0])
#define BP(b, s) (&lds[b][1][s][0])
#define STAGE2(pl, sp)                                                          \
  do {                                                                          \
    __builtin_amdgcn_global_load_lds(                                           \
        (const __attribute__((address_space(1))) unsigned int*)(const void*)(sp),\
        (__attribute__((address_space(3))) unsigned int*)(void*)((pl) + tid * 8),\
        16, 0, 0);                                                              \
    __builtin_amdgcn_global_load_lds(                                           \
        (const __attribute__((address_space(1))) unsigned int*)(const void*)((sp) + (size_t)128 * K_PAD), \
        (__attribute__((address_space(3))) unsigned int*)(void*)((pl) + 4096 + tid * 8), \
        16, 0, 0);                                                              \
  } while (0)
#define LDA4(dst, b, s, MH)                                                     \
  do {                                                                          \
    const char* _p = (const char*)AP(b, s) + wm * 8192 + (MH) * 4096 + laneOff; \
    dst[0] = *(const bf16x8*)(_p);                                              \
    dst[1] = *(const bf16x8*)(_p + 1024);                                       \
    dst[2] = *(const bf16x8*)(_p + 2048);                                       \
    dst[3] = *(const bf16x8*)(_p + 3072);                                       \
  } while (0)
#define LDB4(dst, b, s)                                                         \
  do {                                                                          \
    const char* _p = (const char*)BP(b, s) + wn * 4096 + laneOff;               \
    dst[0] = *(const bf16x8*)(_p);                                              \
    dst[1] = *(const bf16x8*)(_p + 1024);                                       \
    dst[2] = *(const bf16x8*)(_p + 2048);                                       \
    dst[3] = *(const bf16x8*)(_p + 3072);                                       \
  } while (0)
#define MFMA16(MH, av, bv)                                                      \
  do {                                                                          \
    __builtin_amdgcn_s_setprio(1);                                              \
    _Pragma("unroll") for (int _i = 0; _i < 4; ++_i) {                          \
      _Pragma("unroll") for (int _n = 0; _n < 4; ++_n) {                        \
        acc[(MH) * 4 + _i][_n] = __builtin_amdgcn_mfma_f32_16x16x32_bf16(       \
            av[_i], bv[_n], acc[(MH) * 4 + _i][_n], 0, 0, 0);                   \
      }                                                                         \
    }                                                                           \
    __builtin_amdgcn_s_setprio(0);                                              \
  } while (0)
#define BAR()                                                                   \
  do { __builtin_amdgcn_s_barrier(); __builtin_amdgcn_sched_barrier(0); } while (0)
#define VMW(N)                                                                  \
  do { asm volatile("s_waitcnt vmcnt(" #N ")" ::: "memory");                    \
       __builtin_amdgcn_sched_barrier(0); } while (0)

  f32x4 acc[8][4];
#pragma unroll
  for (int m = 0; m < 8; ++m)
#pragma unroll
    for (int n = 0; n < 4; ++n) acc[m][n] = (f32x4)0.f;

  // Prologue: T0 fully (Bk0,Ak0,Bk1,Ak1) + T1 (Bk0,Ak0,Bk1) = 14 loads.
  STAGE2(BP(0, 0), srcB + 0);
  STAGE2(AP(0, 0), srcA + 0);
  STAGE2(BP(0, 1), srcB + 32);
  STAGE2(AP(0, 1), srcA + 32);
  STAGE2(BP(1, 0), srcB + 64);
  STAGE2(AP(1, 0), srcA + 64);
  STAGE2(BP(1, 1), srcB + 96);
  VMW(10);   // T0.Bk0,Ak0 landed
  BAR();

#pragma unroll 1
  for (int it = 0; it < niters; ++it) {
    const bool last = (it == niters - 1);
    const int kT1 = (2 * it + 1) * 64;
    const int kN0 = kT1 + 64;
    const int kN1 = kT1 + 128;
    bf16x8 av[4], bv[4];

    // ---- T0 (buf0) ----
    // P1
    LDB4(bv, 0, 0); LDA4(av, 0, 0, 0);
    STAGE2(AP(1, 1), srcA + kT1 + 32);      // T1.Ak1 (always exists)
    BAR(); MFMA16(0, av, bv); BAR();
    // P2
    LDA4(av, 0, 0, 1);
    if (!last) STAGE2(BP(0, 0), srcB + kN0);
    BAR(); MFMA16(1, av, bv);
    if (last) { VMW(8); } else { VMW(10); }
    BAR();
    // P3
    LDB4(bv, 0, 1); LDA4(av, 0, 1, 0);
    if (!last) STAGE2(AP(0, 0), srcA + kN0);
    BAR(); MFMA16(0, av, bv); BAR();
    // P4
    LDA4(av, 0, 1, 1);
    if (!last) STAGE2(BP(0, 1), srcB + kN0 + 32);
    BAR(); MFMA16(1, av, bv);
    if (last) { VMW(4); } else { VMW(10); }
    BAR();

    // ---- T1 (buf1) ----
    // P5
    LDB4(bv, 1, 0); LDA4(av, 1, 0, 0);
    if (!last) STAGE2(AP(0, 1), srcA + kN0 + 32);
    BAR(); MFMA16(0, av, bv); BAR();
    // P6
    LDA4(av, 1, 0, 1);
    if (!last) STAGE2(BP(1, 0), srcB + kN1);
    BAR(); MFMA16(1, av, bv);
    if (last) { VMW(0); } else { VMW(10); }
    BAR();
    // P7
    LDB4(bv, 1, 1); LDA4(av, 1, 1, 0);
    if (!last) STAGE2(AP(1, 0), srcA + kN1);
    BAR(); MFMA16(0, av, bv); BAR();
    // P8
    LDA4(av, 1, 1, 1);
    if (!last) STAGE2(BP(1, 1), srcB + kN1 + 32);
    BAR(); MFMA16(1, av, bv);
    if (!last) VMW(10);
    BAR();
  }

  // Epilogue: acc[mi][ni] elem j = G(row wm*128+mi*16+g*4+j, col wn*64+ni*16+rl)
  // within tile; rows = (batch, c): batch = tileM*4 + wm*2 + (mi>=4),
  // c = (mi&3)*16 + g*4 + j.
  const int ubase = colB0 + wn * 64;
#pragma unroll
  for (int half = 0; half < 2; ++half) {
    float s[4];
#pragma unroll
    for (int ni = 0; ni < 4; ++ni) {
      const int u = ubase + ni * 16 + rl;
      const float* fwrow = fw + (size_t)u * NC;
      float t = 0.f;
#pragma unroll
      for (int m2 = 0; m2 < 4; ++m2) {
        float4 w4 = *(const float4*)(fwrow + m2 * 16 + g * 4);
        f32x4 a_ = acc[half * 4 + m2][ni];
        t += w4.x * a_[0] + w4.y * a_[1] + w4.z * a_[2] + w4.w * a_[3];
      }
      t += __shfl_xor(t, 16, 64);
      t += __shfl_xor(t, 32, 64);
      s[ni] = t;
    }
    const int bidx = tileM * 4 + wm * 2 + half;
    const int ucol = ubase + lane;   // = ubase + g*16 + rl
    float r = (g == 0) ? s[0] : (g == 1) ? s[1] : (g == 2) ? s[2] : s[3];
    part[((size_t)split * NB + bidx) * NU + ucol] = r;
  }
#undef AP
#undef BP
#undef STAGE2
#undef LDA4
#undef LDB4
#undef MFMA16
#undef BAR
#undef VMW
}

// out[b,u] = part[0][b][u] + part[1][b][u] + bias[u]
__global__ __launch_bounds__(256)
void combine_kernel(const float* __restrict__ part,
                    const float* __restrict__ bias,
                    float* __restrict__ out) {
  int f = blockIdx.x * blockDim.x + threadIdx.x;  // float4 index
  const float4* p0 = (const float4*)part;
  const float4* p1 = (const float4*)(part + (size_t)NB * NU);
  const float4* bz = (const float4*)bias;
  float4 a = p0[f];
  float4 b = p1[f];
  float4 c = bz[f & 511];
  float4 o;
  o.x = a.x + b.x + c.x;
  o.y = a.y + b.y + c.y;
  o.z = a.z + b.z + c.z;
  o.w = a.w + b.w + c.w;
  ((float4*)out)[f] = o;
}

extern "C" void kernel_launch(void* const* d_in, const int* in_sizes, int n_in,
                              void* d_out, int out_size, void* d_ws, size_t ws_size,
                              hipStream_t stream) {
  const float* x    = (const float*)d_in[0];  // [64,64,36,36]
  const float* fw   = (const float*)d_in[1];  // [2048,64,1,1]
  const float* bias = (const float*)d_in[2];  // [2048]
  const float* sw   = (const float*)d_in[3];  // [2048,36,36]
  float* out = (float*)d_out;                 // [64][2048]

  unsigned short* Abf = (unsigned short*)d_ws;            // 4096*1408*2 B
  unsigned short* Bbf = Abf + (size_t)M_ROWS * K_PAD;     // 2048*1408*2 B
  float* part = (float*)(Bbf + (size_t)NU * K_PAD);       // 2*64*2048*4 B

  {
    int total = (M_ROWS + NU) * (K_PAD / 8);
    int blocks = (total + 255) / 256;
    if (blocks > 2048) blocks = 2048;
    convert_pad_kernel<<<blocks, 256, 0, stream>>>(x, sw, Abf);
  }

  // 2 splits x 16 M-tiles x 8 N-tiles = 256 blocks
  fused_readout_gemm<<<dim3(256), 512, 0, stream>>>(Abf, Bbf, fw, part);

  combine_kernel<<<dim3((NB * NU / 4) / 256), 256, 0, stream>>>(part, bias, out);
}